// Round 2
// baseline (1461.706 us; speedup 1.0000x reference)
//
#include <hip/hip_runtime.h>

#define NB 32
#define NA 1024
#define NATOMS (NB*NA)      // 32768
#define D  384
#define H1 256
#define H2 192
#define NE 4

#define TA 32               // atoms per tile
#define KC 32               // K chunk
#define MAXT (NATOMS/TA)    // 1024 tiles/species (worst case: all atoms one species)

#define WS_LD 260           // LDS leading dim for W1 chunk [KC][260] and h1s [TA][260]
#define XS_LD 36            // LDS leading dim for x chunk [TA][36]
#define WH_LD 196           // LDS leading dim for Wh chunk [KC][196]

__global__ void zero_kernel(float* __restrict__ out, int* __restrict__ counts) {
    int i = threadIdx.x;
    if (i < NB) out[i] = 0.0f;
    if (i < NE) counts[i] = 0;
}

__global__ void scatter_kernel(const int* __restrict__ species,
                               int* __restrict__ counts,
                               int* __restrict__ bucket) {
    int i = blockIdx.x * 256 + threadIdx.x;
    if (i < NATOMS) {
        int e = species[i];
        int pos = atomicAdd(&counts[e], 1);   // device-scope
        bucket[(e << 15) + pos] = i;
    }
}

__global__ __launch_bounds__(256, 2) void mlp_kernel(
    const float* __restrict__ rep,      // [B,A,D]
    const int*   __restrict__ counts,   // [E]
    const int*   __restrict__ bucket,   // [E][32768]
    const float* __restrict__ W1,       // [E,D,H1]
    const float* __restrict__ b1,       // [E,H1]
    const float* __restrict__ Wh,       // [E,H1,H2]
    const float* __restrict__ bh,       // [E,H2]
    const float* __restrict__ W2,       // [E,H2]
    const float* __restrict__ b2,       // [E]
    float* __restrict__ out)            // [B]
{
    const int e    = blockIdx.x >> 10;      // 4 species × 1024 tiles
    const int tile = blockIdx.x & 1023;
    const int n    = counts[e];
    const int base = tile * TA;
    if (base >= n) return;

    const int t    = threadIdx.x;
    const int lane = t & 63;
    const int wv   = t >> 6;                // wave id 0..3
    const int hb   = lane * 4;              // phase-1 h columns [hb, hb+4)
    const int ab   = wv * 8;                // this wave's 8 atoms

    __shared__ float bufA[KC * WS_LD];      // W1 chunk, later h1s [TA][WS_LD]
    __shared__ float bufB[KC * WH_LD];      // x chunk (phase1), Wh chunk (phase2)
    __shared__ int   idx_lds[TA];

    if (t < TA) {
        int g = (base + t < n) ? bucket[(e << 15) + base + t] : -1;
        idx_lds[t] = g;
    }
    __syncthreads();

    const float* W1e = W1 + (size_t)e * D * H1;
    const float* Whe = Wh + (size_t)e * H1 * H2;

    // ================= phase 1: h1 = x @ W1[e] + b1[e]  (NO relu — ref quirk)
    float acc1[8][4];
    #pragma unroll
    for (int a = 0; a < 8; ++a)
        acc1[a][0] = acc1[a][1] = acc1[a][2] = acc1[a][3] = 0.0f;

    for (int c = 0; c < D / KC; ++c) {
        const int k0 = c * KC;
        __syncthreads();
        // stage x chunk: [TA][KC] — 256 float4, 1 per thread
        {
            int a = t >> 3, c4 = t & 7;
            int g = idx_lds[a]; if (g < 0) g = 0;
            float4 v = *(const float4*)(rep + (size_t)g * D + k0 + c4 * 4);
            *(float4*)(bufB + a * XS_LD + c4 * 4) = v;
        }
        // stage W1 chunk: [KC][H1] — 2048 float4, 8 per thread
        #pragma unroll
        for (int i = 0; i < 8; ++i) {
            int f4 = i * 256 + t;
            int row = f4 >> 6, col4 = f4 & 63;
            float4 v = *(const float4*)(W1e + (size_t)(k0 + row) * H1 + col4 * 4);
            *(float4*)(bufA + row * WS_LD + col4 * 4) = v;
        }
        __syncthreads();

        #pragma unroll
        for (int kk4 = 0; kk4 < KC / 4; ++kk4) {
            float4 wr0 = *(const float4*)(bufA + (kk4 * 4 + 0) * WS_LD + hb);
            float4 wr1 = *(const float4*)(bufA + (kk4 * 4 + 1) * WS_LD + hb);
            float4 wr2 = *(const float4*)(bufA + (kk4 * 4 + 2) * WS_LD + hb);
            float4 wr3 = *(const float4*)(bufA + (kk4 * 4 + 3) * WS_LD + hb);
            #pragma unroll
            for (int a = 0; a < 8; ++a) {
                float4 xv = *(const float4*)(bufB + (ab + a) * XS_LD + kk4 * 4);
                acc1[a][0] += xv.x*wr0.x + xv.y*wr1.x + xv.z*wr2.x + xv.w*wr3.x;
                acc1[a][1] += xv.x*wr0.y + xv.y*wr1.y + xv.z*wr2.y + xv.w*wr3.y;
                acc1[a][2] += xv.x*wr0.z + xv.y*wr1.z + xv.z*wr2.z + xv.w*wr3.z;
                acc1[a][3] += xv.x*wr0.w + xv.y*wr1.w + xv.z*wr2.w + xv.w*wr3.w;
            }
        }
    }
    // + b1 (no activation)
    {
        float4 bv = *(const float4*)(b1 + e * H1 + hb);
        #pragma unroll
        for (int a = 0; a < 8; ++a) {
            acc1[a][0] += bv.x; acc1[a][1] += bv.y;
            acc1[a][2] += bv.z; acc1[a][3] += bv.w;
        }
    }
    // write h1 tile into bufA (reuse)
    __syncthreads();
    #pragma unroll
    for (int a = 0; a < 8; ++a) {
        float4 v = make_float4(acc1[a][0], acc1[a][1], acc1[a][2], acc1[a][3]);
        *(float4*)(bufA + (ab + a) * WS_LD + hb) = v;
    }

    // ================= phase 2: h2 = relu(h1 @ Wh[e] + bh[e]); energy = h2·W2[e]
    float acc2[8][3];
    #pragma unroll
    for (int a = 0; a < 8; ++a)
        acc2[a][0] = acc2[a][1] = acc2[a][2] = 0.0f;

    for (int c = 0; c < H1 / KC; ++c) {
        const int h0 = c * KC;
        __syncthreads();
        // stage Wh chunk: [KC][H2] — 1536 float4, 6 per thread
        #pragma unroll
        for (int i = 0; i < 6; ++i) {
            int f4 = i * 256 + t;
            int row = f4 / 48, col4 = f4 % 48;
            float4 v = *(const float4*)(Whe + (size_t)(h0 + row) * H2 + col4 * 4);
            *(float4*)(bufB + row * WH_LD + col4 * 4) = v;
        }
        __syncthreads();

        #pragma unroll
        for (int kk4 = 0; kk4 < KC / 4; ++kk4) {
            float w[4][3];
            #pragma unroll
            for (int dk = 0; dk < 4; ++dk) {
                const float* wp = bufB + (kk4 * 4 + dk) * WH_LD + lane;
                w[dk][0] = wp[0]; w[dk][1] = wp[64]; w[dk][2] = wp[128];
            }
            #pragma unroll
            for (int a = 0; a < 8; ++a) {
                float4 hv = *(const float4*)(bufA + (ab + a) * WS_LD + h0 + kk4 * 4);
                acc2[a][0] += hv.x*w[0][0] + hv.y*w[1][0] + hv.z*w[2][0] + hv.w*w[3][0];
                acc2[a][1] += hv.x*w[0][1] + hv.y*w[1][1] + hv.z*w[2][1] + hv.w*w[3][1];
                acc2[a][2] += hv.x*w[0][2] + hv.y*w[1][2] + hv.z*w[2][2] + hv.w*w[3][2];
            }
        }
    }

    // ================= epilogue: relu, dot W2, +b2, reduce over lanes, scatter
    const float* bhe = bh + e * H2;
    const float* w2e = W2 + e * H2;
    float wb[3], w2v[3];
    #pragma unroll
    for (int m = 0; m < 3; ++m) {
        wb[m]  = bhe[lane + 64 * m];
        w2v[m] = w2e[lane + 64 * m];
    }
    const float b2e = b2[e];

    #pragma unroll
    for (int a = 0; a < 8; ++a) {
        float v = 0.0f;
        #pragma unroll
        for (int m = 0; m < 3; ++m) {
            float z = acc2[a][m] + wb[m];
            z = fmaxf(z, 0.0f);
            v += z * w2v[m];
        }
        for (int off = 32; off > 0; off >>= 1)
            v += __shfl_down(v, off, 64);
        if (lane == 0) {
            int g = idx_lds[ab + a];
            if (g >= 0) atomicAdd(&out[g >> 10], v + b2e);
        }
    }
}

extern "C" void kernel_launch(void* const* d_in, const int* in_sizes, int n_in,
                              void* d_out, int out_size, void* d_ws, size_t ws_size,
                              hipStream_t stream) {
    const float* rep     = (const float*)d_in[0];
    const int*   species = (const int*)  d_in[1];
    const float* W1      = (const float*)d_in[2];
    const float* b1      = (const float*)d_in[3];
    const float* Wh      = (const float*)d_in[4];
    const float* bh      = (const float*)d_in[5];
    const float* W2      = (const float*)d_in[6];
    const float* b2      = (const float*)d_in[7];
    float* out = (float*)d_out;

    int* counts = (int*)d_ws;           // [4]
    int* bucket = counts + 4;           // [4][32768]  (uses ~512 KB of d_ws)

    zero_kernel<<<1, 64, 0, stream>>>(out, counts);
    scatter_kernel<<<NATOMS / 256, 256, 0, stream>>>(species, counts, bucket);
    mlp_kernel<<<NE * MAXT, 256, 0, stream>>>(
        rep, counts, bucket, W1, b1, Wh, bh, W2, b2, out);
}

// Round 3
// 314.136 us; speedup vs baseline: 4.6531x; 4.6531x over previous
//
#include <hip/hip_runtime.h>

typedef __attribute__((ext_vector_type(8))) short bf16x8;
typedef __attribute__((ext_vector_type(4))) float f32x4;
typedef unsigned short ushort_t;

#define NB 32
#define NA 1024
#define NATOMS (NB*NA)
#define D  384
#define H1 256
#define H2 192
#define NE 4
#define TA 64                 // atoms per tile
#define MAXT 512              // max tiles per species

// LDS row strides (bf16 elements) — padded for bank spread
#define XLD  40               // X tile  [64][40]
#define WLD  40               // W tile  [256][40]
#define HLD  264              // H1 tile [64][264]

__device__ __forceinline__ ushort_t f2bf(float f) {
    union { float f; unsigned u; } v; v.f = f;
    unsigned r = v.u + 0x7FFF + ((v.u >> 16) & 1);   // RNE
    return (ushort_t)(r >> 16);
}

__global__ void zero_kernel(int* __restrict__ counts) {
    if (threadIdx.x < NE) counts[threadIdx.x] = 0;
}

__global__ void scatter_kernel(const int* __restrict__ species,
                               int* __restrict__ counts,
                               int* __restrict__ bucket) {
    int i = blockIdx.x * 256 + threadIdx.x;
    if (i < NATOMS) {
        int e = species[i];
        int pos = atomicAdd(&counts[e], 1);
        bucket[(e << 15) + pos] = i;
    }
}

// Convert + transpose weights to bf16: w1t[e][c][k] = W1[e][k][c], wht[e][c][k] = Wh[e][k][c]
__global__ void prep_kernel(const float* __restrict__ W1, const float* __restrict__ Wh,
                            ushort_t* __restrict__ w1t, ushort_t* __restrict__ wht) {
    int i = blockIdx.x * 256 + threadIdx.x;
    if (i < NE * H1 * D) {                    // 393216
        int e = i / (H1 * D);
        int rem = i % (H1 * D);
        int c = rem / D, k = rem % D;
        w1t[i] = f2bf(W1[((size_t)e * D + k) * H1 + c]);
    } else {
        int j = i - NE * H1 * D;
        if (j < NE * H2 * H1) {               // 196608
            int e = j / (H2 * H1);
            int rem = j % (H2 * H1);
            int c = rem / H1, k = rem % H1;
            wht[j] = f2bf(Wh[((size_t)e * H1 + k) * H2 + c]);
        }
    }
}

__global__ __launch_bounds__(256, 2) void mlp_kernel(
    const float*   __restrict__ rep,      // [B,A,D] fp32
    const int*     __restrict__ counts,   // [E]
    const int*     __restrict__ bucket,   // [E][32768]
    const ushort_t* __restrict__ w1t,     // [E][H1][D]  bf16 (transposed)
    const ushort_t* __restrict__ wht,     // [E][H2][H1] bf16 (transposed)
    const float*   __restrict__ b1,       // [E,H1]
    const float*   __restrict__ bh,       // [E,H2]
    const float*   __restrict__ W2,       // [E,H2]
    const float*   __restrict__ b2,       // [E]
    float*         __restrict__ energy)   // [NATOMS] per-atom energies
{
    const int e    = blockIdx.x >> 9;
    const int tile = blockIdx.x & 511;
    const int n    = counts[e];
    const int base = tile * TA;
    if (base >= n) return;

    const int t    = threadIdx.x;
    const int lane = t & 63;
    const int wv   = t >> 6;        // wave 0..3
    const int g    = lane >> 4;     // k-group 0..3
    const int r    = lane & 15;     // row/col within 16

    __shared__ ushort_t Wt[H1 * WLD];     // 20 KB  — W1/Wh k-slice
    __shared__ ushort_t Xt[TA * XLD];     // 5 KB   — X k-slice (bf16)
    __shared__ ushort_t H1t[TA * HLD];    // 33 KB  — h1 tile (bf16)
    __shared__ float    eparts[4 * TA];   // 1 KB
    __shared__ int      idx_lds[TA];

    if (t < TA)
        idx_lds[t] = (base + t < n) ? bucket[(e << 15) + base + t] : -1;

    const ushort_t* W1T = w1t + (size_t)e * H1 * D;     // row stride D
    const ushort_t* WhT = wht + (size_t)e * H2 * H1;    // row stride H1

    // ================= phase 1: C1[64x256] = X[64x384] @ W1  (+b1, NO relu)
    f32x4 acc1[4][4];
    #pragma unroll
    for (int m = 0; m < 4; ++m)
        #pragma unroll
        for (int nn = 0; nn < 4; ++nn)
            acc1[m][nn] = (f32x4){0.f, 0.f, 0.f, 0.f};

    for (int ks = 0; ks < D / 32; ++ks) {
        const int k0 = ks * 32;
        __syncthreads();
        // stage X[64][32] bf16: 512 float4 loads, 2/thread, convert on the fly
        #pragma unroll
        for (int i = 0; i < 2; ++i) {
            int c = i * 256 + t;
            int row = c >> 3, c4 = c & 7;
            int gi = idx_lds[row]; if (gi < 0) gi = 0;
            float4 v = *(const float4*)(rep + (size_t)gi * D + k0 + c4 * 4);
            ushort4 o;
            o.x = f2bf(v.x); o.y = f2bf(v.y); o.z = f2bf(v.z); o.w = f2bf(v.w);
            *(ushort4*)(Xt + row * XLD + c4 * 4) = o;
        }
        // stage W1T[256 cols][32 k]: 1024 16B chunks, 4/thread
        #pragma unroll
        for (int i = 0; i < 4; ++i) {
            int c = i * 256 + t;
            int row = c >> 2, c8 = c & 3;
            uint4 v = *(const uint4*)(W1T + (size_t)row * D + k0 + c8 * 8);
            *(uint4*)(Wt + row * WLD + c8 * 8) = v;
        }
        __syncthreads();

        bf16x8 af[4], bw[4];
        #pragma unroll
        for (int m = 0; m < 4; ++m)
            af[m] = *(const bf16x8*)(Xt + (m * 16 + r) * XLD + g * 8);
        #pragma unroll
        for (int nn = 0; nn < 4; ++nn)
            bw[nn] = *(const bf16x8*)(Wt + (wv * 64 + nn * 16 + r) * WLD + g * 8);
        #pragma unroll
        for (int m = 0; m < 4; ++m)
            #pragma unroll
            for (int nn = 0; nn < 4; ++nn)
                acc1[m][nn] = __builtin_amdgcn_mfma_f32_16x16x32_bf16(
                    af[m], bw[nn], acc1[m][nn], 0, 0, 0);
    }

    // +b1, convert to bf16, write H1 tile (C layout: row=4g+reg within 16; col=r)
    #pragma unroll
    for (int nn = 0; nn < 4; ++nn) {
        int col = wv * 64 + nn * 16 + r;
        float bb = b1[e * H1 + col];
        #pragma unroll
        for (int m = 0; m < 4; ++m) {
            #pragma unroll
            for (int q = 0; q < 4; ++q) {
                int row = m * 16 + g * 4 + q;
                H1t[row * HLD + col] = f2bf(acc1[m][nn][q] + bb);
            }
        }
    }

    // ================= phase 2: C2[64x192] = H1[64x256] @ Wh
    f32x4 acc2[4][3];
    #pragma unroll
    for (int m = 0; m < 4; ++m)
        #pragma unroll
        for (int nn = 0; nn < 3; ++nn)
            acc2[m][nn] = (f32x4){0.f, 0.f, 0.f, 0.f};

    for (int ks = 0; ks < H1 / 32; ++ks) {
        const int k0 = ks * 32;
        __syncthreads();   // waves done with Wt (and, at ks=0, H1t fully written)
        // stage WhT[192 cols][32 k]: 768 16B chunks, 3/thread
        #pragma unroll
        for (int i = 0; i < 3; ++i) {
            int c = i * 256 + t;
            int row = c >> 2, c8 = c & 3;
            uint4 v = *(const uint4*)(WhT + (size_t)row * H1 + k0 + c8 * 8);
            *(uint4*)(Wt + row * WLD + c8 * 8) = v;
        }
        __syncthreads();

        bf16x8 af[4], bw[3];
        #pragma unroll
        for (int m = 0; m < 4; ++m)
            af[m] = *(const bf16x8*)(H1t + (m * 16 + r) * HLD + k0 + g * 8);
        #pragma unroll
        for (int nn = 0; nn < 3; ++nn)
            bw[nn] = *(const bf16x8*)(Wt + (wv * 48 + nn * 16 + r) * WLD + g * 8);
        #pragma unroll
        for (int m = 0; m < 4; ++m)
            #pragma unroll
            for (int nn = 0; nn < 3; ++nn)
                acc2[m][nn] = __builtin_amdgcn_mfma_f32_16x16x32_bf16(
                    af[m], bw[nn], acc2[m][nn], 0, 0, 0);
    }

    // ================= epilogue: relu(c2+bh)·W2, reduce over cols, store energies
    float bhv[3], w2v[3];
    #pragma unroll
    for (int nn = 0; nn < 3; ++nn) {
        int col = wv * 48 + nn * 16 + r;
        bhv[nn] = bh[e * H2 + col];
        w2v[nn] = W2[e * H2 + col];
    }

    #pragma unroll
    for (int m = 0; m < 4; ++m) {
        #pragma unroll
        for (int q = 0; q < 4; ++q) {
            float s = 0.f;
            #pragma unroll
            for (int nn = 0; nn < 3; ++nn) {
                float z = acc2[m][nn][q] + bhv[nn];
                z = fmaxf(z, 0.f);
                s += z * w2v[nn];
            }
            s += __shfl_xor(s, 1, 64);
            s += __shfl_xor(s, 2, 64);
            s += __shfl_xor(s, 4, 64);
            s += __shfl_xor(s, 8, 64);
            if (r == 0)
                eparts[wv * TA + m * 16 + g * 4 + q] = s;
        }
    }
    __syncthreads();
    if (t < TA) {
        int gi = idx_lds[t];
        if (gi >= 0) {
            float tot = eparts[t] + eparts[TA + t] + eparts[2 * TA + t] + eparts[3 * TA + t];
            energy[gi] = tot + b2[e];
        }
    }
}

__global__ void reduce_kernel(const float* __restrict__ energy, float* __restrict__ out) {
    const int b = blockIdx.x, t = threadIdx.x;
    float s = 0.f;
    for (int i = t; i < NA; i += 256) s += energy[b * NA + i];
    for (int off = 32; off > 0; off >>= 1) s += __shfl_down(s, off, 64);
    __shared__ float ws[4];
    if ((t & 63) == 0) ws[t >> 6] = s;
    __syncthreads();
    if (t == 0) out[b] = ws[0] + ws[1] + ws[2] + ws[3];
}

extern "C" void kernel_launch(void* const* d_in, const int* in_sizes, int n_in,
                              void* d_out, int out_size, void* d_ws, size_t ws_size,
                              hipStream_t stream) {
    const float* rep     = (const float*)d_in[0];
    const int*   species = (const int*)  d_in[1];
    const float* W1      = (const float*)d_in[2];
    const float* b1      = (const float*)d_in[3];
    const float* Wh      = (const float*)d_in[4];
    const float* bh      = (const float*)d_in[5];
    const float* W2      = (const float*)d_in[6];
    const float* b2      = (const float*)d_in[7];
    float* out = (float*)d_out;

    char* ws = (char*)d_ws;
    int*      counts  = (int*)      (ws + 0);
    int*      bucket  = (int*)      (ws + 64);          // 512 KB
    float*    energy  = (float*)    (ws + 524352);      // 128 KB
    ushort_t* w1t     = (ushort_t*) (ws + 655424);      // 768 KB
    ushort_t* wht     = (ushort_t*) (ws + 1441856);     // 384 KB  (total ~1.8 MB)

    zero_kernel<<<1, 64, 0, stream>>>(counts);
    scatter_kernel<<<NATOMS / 256, 256, 0, stream>>>(species, counts, bucket);
    prep_kernel<<<(NE * H1 * D + NE * H2 * H1 + 255) / 256, 256, 0, stream>>>(W1, Wh, w1t, wht);
    mlp_kernel<<<NE * MAXT, 256, 0, stream>>>(rep, counts, bucket, w1t, wht,
                                              b1, bh, W2, b2, energy);
    reduce_kernel<<<NB, 256, 0, stream>>>(energy, out);
}

// Round 4
// 167.304 us; speedup vs baseline: 8.7368x; 1.8776x over previous
//
#include <hip/hip_runtime.h>

typedef __attribute__((ext_vector_type(8))) short bf16x8;
typedef __attribute__((ext_vector_type(4))) float f32x4;
typedef unsigned short ushort_t;

#define NB 32
#define NA 1024
#define NATOMS (NB*NA)
#define D  384
#define H1 256
#define H2 192
#define NE 4
#define TA 64                 // atoms per tile
#define MAXT 512              // max tiles per species

#define XLD  40               // X tile  [64][40] bf16
#define WLD  40               // W tile  [256][40] bf16
#define HLD  264              // H1 tile [64][264] bf16

__device__ __forceinline__ ushort_t f2bf(float f) {
    union { float f; unsigned u; } v; v.f = f;
    unsigned r = v.u + 0x7FFF + ((v.u >> 16) & 1);   // RNE
    return (ushort_t)(r >> 16);
}

__global__ void zero_kernel(int* __restrict__ counts) {
    if (threadIdx.x < NE) counts[threadIdx.x] = 0;
}

// ---- scatter: per-wave ballot histogram -> per-block bases -> 4 atomics/block
__global__ __launch_bounds__(256) void scatter_kernel(
    const int* __restrict__ species, int* __restrict__ counts, int* __restrict__ bucket)
{
    __shared__ int wcnt[4][4];    // [wave][species]
    __shared__ int wbase[4][4];
    const int t = threadIdx.x, lane = t & 63, wv = t >> 6;
    const int i = blockIdx.x * 256 + t;
    const int e = species[i];

    unsigned long long m0 = __ballot(e == 0);
    unsigned long long m1 = __ballot(e == 1);
    unsigned long long m2 = __ballot(e == 2);
    unsigned long long m3 = __ballot(e == 3);
    unsigned long long mym = (e == 0) ? m0 : (e == 1) ? m1 : (e == 2) ? m2 : m3;
    const unsigned long long lt = (lane == 63) ? 0x7FFFFFFFFFFFFFFFull
                                               : ((1ull << lane) - 1ull);
    const int rank = __popcll(mym & lt);

    if (lane == 0) {
        wcnt[wv][0] = __popcll(m0); wcnt[wv][1] = __popcll(m1);
        wcnt[wv][2] = __popcll(m2); wcnt[wv][3] = __popcll(m3);
    }
    __syncthreads();
    if (t < NE) {   // one thread per species
        int s = t;
        int tot = wcnt[0][s] + wcnt[1][s] + wcnt[2][s] + wcnt[3][s];
        int base = atomicAdd(&counts[s], tot);
        for (int w = 0; w < 4; ++w) { wbase[w][s] = base; base += wcnt[w][s]; }
    }
    __syncthreads();
    bucket[(e << 15) + wbase[wv][e] + rank] = i;
}

// ---- coalesced transpose+convert: dst[e][c][k] = bf16(src[e][k][c]); 32x32 tiles
__global__ __launch_bounds__(256) void transpose_kernel(
    const float* __restrict__ src, ushort_t* __restrict__ dst,
    int R, int C, int nrt, int nct)
{
    __shared__ float tile[32][33];
    const int t = threadIdx.x;
    int bid = blockIdx.x;
    int e   = bid / (nrt * nct);
    int rem = bid % (nrt * nct);
    int rt  = rem / nct, ct = rem % nct;
    const float* S = src + ((size_t)e * R + rt * 32) * C + ct * 32;
    ushort_t*    Dp = dst + ((size_t)e * C + ct * 32) * R + rt * 32;

    {
        int row = t >> 3, c4 = (t & 7) * 4;
        float4 v = *(const float4*)(S + (size_t)row * C + c4);
        tile[row][c4 + 0] = v.x; tile[row][c4 + 1] = v.y;
        tile[row][c4 + 2] = v.z; tile[row][c4 + 3] = v.w;
    }
    __syncthreads();
    {
        int orow = t >> 3, k4 = (t & 7) * 4;   // orow = c index, k4 = k offset
        ushort4 o;
        o.x = f2bf(tile[k4 + 0][orow]);
        o.y = f2bf(tile[k4 + 1][orow]);
        o.z = f2bf(tile[k4 + 2][orow]);
        o.w = f2bf(tile[k4 + 3][orow]);
        *(ushort4*)(Dp + (size_t)orow * R + k4) = o;
    }
}

__global__ __launch_bounds__(256, 2) void mlp_kernel(
    const float*    __restrict__ rep,      // [B,A,D] fp32
    const int*      __restrict__ counts,   // [E]
    const int*      __restrict__ bucket,   // [E][32768]
    const ushort_t* __restrict__ w1t,      // [E][H1][D]  bf16 (transposed)
    const ushort_t* __restrict__ wht,      // [E][H2][H1] bf16 (transposed)
    const float*    __restrict__ b1,       // [E,H1]
    const float*    __restrict__ bh,       // [E,H2]
    const float*    __restrict__ W2,       // [E,H2]
    const float*    __restrict__ b2,       // [E]
    float*          __restrict__ energy)   // [NATOMS]
{
    const int e    = blockIdx.x >> 9;
    const int tile = blockIdx.x & 511;
    const int n    = counts[e];
    const int base = tile * TA;
    if (base >= n) return;

    const int t    = threadIdx.x;
    const int lane = t & 63;
    const int wv   = t >> 6;
    const int g    = lane >> 4;
    const int r    = lane & 15;

    __shared__ ushort_t Wt[H1 * WLD];
    __shared__ ushort_t Xt[TA * XLD];
    __shared__ ushort_t H1t[TA * HLD];
    __shared__ float    eparts[4 * TA];
    __shared__ int      idx_lds[TA];

    if (t < TA)
        idx_lds[t] = (base + t < n) ? bucket[(e << 15) + base + t] : -1;
    __syncthreads();

    const ushort_t* W1T = w1t + (size_t)e * H1 * D;
    const ushort_t* WhT = wht + (size_t)e * H2 * H1;

    // per-thread constant staging coordinates
    const int xrow0 = t >> 3;            // 0..31
    const int xrow1 = 32 + xrow0;        // 32..63
    const int xc4   = (t & 7) * 4;       // k offset within 32-chunk
    int gi0 = idx_lds[xrow0]; if (gi0 < 0) gi0 = 0;
    int gi1 = idx_lds[xrow1]; if (gi1 < 0) gi1 = 0;
    const float* xp0 = rep + (size_t)gi0 * D + xc4;
    const float* xp1 = rep + (size_t)gi1 * D + xc4;
    const int wrow = t >> 2;             // base W row (i adds 64)
    const int wc8  = (t & 3) * 8;        // k offset within 32-chunk

    // ========== phase 1: C1[64x256] = X @ W1 (+b1, NO relu — ref quirk)
    float4 rx0, rx1; uint4 rw[4];
    rx0 = *(const float4*)(xp0);
    rx1 = *(const float4*)(xp1);
    #pragma unroll
    for (int i = 0; i < 4; ++i)
        rw[i] = *(const uint4*)(W1T + (size_t)(wrow + i * 64) * D + wc8);

    f32x4 acc1[4][4];
    #pragma unroll
    for (int m = 0; m < 4; ++m)
        #pragma unroll
        for (int nn = 0; nn < 4; ++nn)
            acc1[m][nn] = (f32x4){0.f, 0.f, 0.f, 0.f};

    for (int ks = 0; ks < D / 32; ++ks) {
        __syncthreads();                       // prev compute done, LDS free
        {
            ushort4 o;
            o.x = f2bf(rx0.x); o.y = f2bf(rx0.y); o.z = f2bf(rx0.z); o.w = f2bf(rx0.w);
            *(ushort4*)(Xt + xrow0 * XLD + xc4) = o;
            o.x = f2bf(rx1.x); o.y = f2bf(rx1.y); o.z = f2bf(rx1.z); o.w = f2bf(rx1.w);
            *(ushort4*)(Xt + xrow1 * XLD + xc4) = o;
        }
        #pragma unroll
        for (int i = 0; i < 4; ++i)
            *(uint4*)(Wt + (wrow + i * 64) * WLD + wc8) = rw[i];
        __syncthreads();                       // staged

        if (ks + 1 < D / 32) {                 // T14: issue next-step loads now
            const int k0n = (ks + 1) * 32;
            rx0 = *(const float4*)(xp0 + k0n);
            rx1 = *(const float4*)(xp1 + k0n);
            #pragma unroll
            for (int i = 0; i < 4; ++i)
                rw[i] = *(const uint4*)(W1T + (size_t)(wrow + i * 64) * D + k0n + wc8);
        }

        bf16x8 af[4], bw[4];
        #pragma unroll
        for (int m = 0; m < 4; ++m)
            af[m] = *(const bf16x8*)(Xt + (m * 16 + r) * XLD + g * 8);
        #pragma unroll
        for (int nn = 0; nn < 4; ++nn)
            bw[nn] = *(const bf16x8*)(Wt + (wv * 64 + nn * 16 + r) * WLD + g * 8);
        #pragma unroll
        for (int m = 0; m < 4; ++m)
            #pragma unroll
            for (int nn = 0; nn < 4; ++nn)
                acc1[m][nn] = __builtin_amdgcn_mfma_f32_16x16x32_bf16(
                    af[m], bw[nn], acc1[m][nn], 0, 0, 0);
    }

    // phase-2 prologue loads (independent of acc1) — hide under epilogue VALU
    uint4 rwh[3];
    #pragma unroll
    for (int i = 0; i < 3; ++i)
        rwh[i] = *(const uint4*)(WhT + (size_t)(wrow + i * 64) * H1 + wc8);

    // +b1, convert, write H1 tile (C layout: row = m*16 + g*4 + q, col per nn)
    #pragma unroll
    for (int nn = 0; nn < 4; ++nn) {
        int col = wv * 64 + nn * 16 + r;
        float bb = b1[e * H1 + col];
        #pragma unroll
        for (int m = 0; m < 4; ++m)
            #pragma unroll
            for (int q = 0; q < 4; ++q)
                H1t[(m * 16 + g * 4 + q) * HLD + col] = f2bf(acc1[m][nn][q] + bb);
    }

    // ========== phase 2: C2[64x192] = H1 @ Wh
    f32x4 acc2[4][3];
    #pragma unroll
    for (int m = 0; m < 4; ++m)
        #pragma unroll
        for (int nn = 0; nn < 3; ++nn)
            acc2[m][nn] = (f32x4){0.f, 0.f, 0.f, 0.f};

    for (int ks = 0; ks < H1 / 32; ++ks) {
        const int k0 = ks * 32;
        __syncthreads();                       // all waves done reading Wt (and H1t staged at ks=0)
        #pragma unroll
        for (int i = 0; i < 3; ++i)
            *(uint4*)(Wt + (wrow + i * 64) * WLD + wc8) = rwh[i];
        __syncthreads();

        if (ks + 1 < H1 / 32) {
            const int k0n = (ks + 1) * 32;
            #pragma unroll
            for (int i = 0; i < 3; ++i)
                rwh[i] = *(const uint4*)(WhT + (size_t)(wrow + i * 64) * H1 + k0n + wc8);
        }

        bf16x8 af[4], bw[3];
        #pragma unroll
        for (int m = 0; m < 4; ++m)
            af[m] = *(const bf16x8*)(H1t + (m * 16 + r) * HLD + k0 + g * 8);
        #pragma unroll
        for (int nn = 0; nn < 3; ++nn)
            bw[nn] = *(const bf16x8*)(Wt + (wv * 48 + nn * 16 + r) * WLD + g * 8);
        #pragma unroll
        for (int m = 0; m < 4; ++m)
            #pragma unroll
            for (int nn = 0; nn < 3; ++nn)
                acc2[m][nn] = __builtin_amdgcn_mfma_f32_16x16x32_bf16(
                    af[m], bw[nn], acc2[m][nn], 0, 0, 0);
    }

    // ========== epilogue: relu(c2+bh)·W2, reduce over cols, store per-atom energy
    float bhv[3], w2v[3];
    #pragma unroll
    for (int nn = 0; nn < 3; ++nn) {
        int col = wv * 48 + nn * 16 + r;
        bhv[nn] = bh[e * H2 + col];
        w2v[nn] = W2[e * H2 + col];
    }

    #pragma unroll
    for (int m = 0; m < 4; ++m) {
        #pragma unroll
        for (int q = 0; q < 4; ++q) {
            float s = 0.f;
            #pragma unroll
            for (int nn = 0; nn < 3; ++nn) {
                float z = acc2[m][nn][q] + bhv[nn];
                z = fmaxf(z, 0.f);
                s += z * w2v[nn];
            }
            s += __shfl_xor(s, 1, 64);
            s += __shfl_xor(s, 2, 64);
            s += __shfl_xor(s, 4, 64);
            s += __shfl_xor(s, 8, 64);
            if (r == 0)
                eparts[wv * TA + m * 16 + g * 4 + q] = s;
        }
    }
    __syncthreads();
    if (t < TA) {
        int gi = idx_lds[t];
        if (gi >= 0) {
            float tot = eparts[t] + eparts[TA + t] + eparts[2 * TA + t] + eparts[3 * TA + t];
            energy[gi] = tot + b2[e];
        }
    }
}

__global__ void reduce_kernel(const float* __restrict__ energy, float* __restrict__ out) {
    const int b = blockIdx.x, t = threadIdx.x;
    float s = 0.f;
    for (int i = t; i < NA; i += 256) s += energy[b * NA + i];
    for (int off = 32; off > 0; off >>= 1) s += __shfl_down(s, off, 64);
    __shared__ float ws[4];
    if ((t & 63) == 0) ws[t >> 6] = s;
    __syncthreads();
    if (t == 0) out[b] = ws[0] + ws[1] + ws[2] + ws[3];
}

extern "C" void kernel_launch(void* const* d_in, const int* in_sizes, int n_in,
                              void* d_out, int out_size, void* d_ws, size_t ws_size,
                              hipStream_t stream) {
    const float* rep     = (const float*)d_in[0];
    const int*   species = (const int*)  d_in[1];
    const float* W1      = (const float*)d_in[2];
    const float* b1      = (const float*)d_in[3];
    const float* Wh      = (const float*)d_in[4];
    const float* bh      = (const float*)d_in[5];
    const float* W2      = (const float*)d_in[6];
    const float* b2      = (const float*)d_in[7];
    float* out = (float*)d_out;

    char* ws = (char*)d_ws;
    int*      counts  = (int*)      (ws + 0);
    int*      bucket  = (int*)      (ws + 64);          // 512 KB
    float*    energy  = (float*)    (ws + 524352);      // 128 KB
    ushort_t* w1t     = (ushort_t*) (ws + 655424);      // 768 KB
    ushort_t* wht     = (ushort_t*) (ws + 1441856);     // 384 KB

    zero_kernel<<<1, 64, 0, stream>>>(counts);
    scatter_kernel<<<NATOMS / 256, 256, 0, stream>>>(species, counts, bucket);
    // W1: [E][384][256] -> [E][256][384];  Wh: [E][256][192] -> [E][192][256]
    transpose_kernel<<<NE * 12 * 8, 256, 0, stream>>>(W1, w1t, D, H1, 12, 8);
    transpose_kernel<<<NE * 8 * 6, 256, 0, stream>>>(Wh, wht, H1, H2, 8, 6);
    mlp_kernel<<<NE * MAXT, 256, 0, stream>>>(rep, counts, bucket, w1t, wht,
                                              b1, bh, W2, b2, energy);
    reduce_kernel<<<NB, 256, 0, stream>>>(energy, out);
}

// Round 5
// 125.475 us; speedup vs baseline: 11.6494x; 1.3334x over previous
//
#include <hip/hip_runtime.h>

typedef __attribute__((ext_vector_type(8))) short bf16x8;
typedef __attribute__((ext_vector_type(4))) float f32x4;
typedef unsigned short ushort_t;

#define NB 32
#define NA 1024
#define NATOMS (NB*NA)
#define D  384
#define H1 256
#define H2 192
#define NE 4
#define TA 64
#define NGRID 515            // max sum of ceil(n_e/64) over 4 species

#define XLD 40               // X tile row stride (bf16)
#define HLD 264              // H1 tile row stride (bf16)

__device__ __forceinline__ ushort_t f2bf(float f) {
    union { float f; unsigned u; } v; v.f = f;
    unsigned r = v.u + 0x7FFF + ((v.u >> 16) & 1);   // RNE
    return (ushort_t)(r >> 16);
}

__global__ void zero_kernel(int* __restrict__ counts) {
    if (threadIdx.x < NE) counts[threadIdx.x] = 0;
}

// per-wave ballot histogram -> 4 atomics per block -> rank write
__global__ __launch_bounds__(256) void scatter_kernel(
    const int* __restrict__ species, int* __restrict__ counts, int* __restrict__ bucket)
{
    __shared__ int wcnt[4][4];
    __shared__ int wbase[4][4];
    const int t = threadIdx.x, lane = t & 63, wv = t >> 6;
    const int i = blockIdx.x * 256 + t;
    const int e = species[i];

    unsigned long long m0 = __ballot(e == 0);
    unsigned long long m1 = __ballot(e == 1);
    unsigned long long m2 = __ballot(e == 2);
    unsigned long long m3 = __ballot(e == 3);
    unsigned long long mym = (e == 0) ? m0 : (e == 1) ? m1 : (e == 2) ? m2 : m3;
    const unsigned long long lt = (lane == 63) ? 0x7FFFFFFFFFFFFFFFull
                                               : ((1ull << lane) - 1ull);
    const int rank = __popcll(mym & lt);

    if (lane == 0) {
        wcnt[wv][0] = __popcll(m0); wcnt[wv][1] = __popcll(m1);
        wcnt[wv][2] = __popcll(m2); wcnt[wv][3] = __popcll(m3);
    }
    __syncthreads();
    if (t < NE) {
        int s = t;
        int tot = wcnt[0][s] + wcnt[1][s] + wcnt[2][s] + wcnt[3][s];
        int b = atomicAdd(&counts[s], tot);
        for (int w = 0; w < 4; ++w) { wbase[w][s] = b; b += wcnt[w][s]; }
    }
    __syncthreads();
    bucket[(e << 15) + wbase[wv][e] + rank] = i;
}

// fused transpose+convert for W1 and Wh: dst[e][c][k] = bf16(src[e][k][c])
__global__ __launch_bounds__(256) void transpose_kernel(
    const float* __restrict__ W1, const float* __restrict__ Wh,
    ushort_t* __restrict__ w1t, ushort_t* __restrict__ wht)
{
    __shared__ float tile[32][33];
    const int t = threadIdx.x;
    int bid = blockIdx.x;
    const float* src; ushort_t* dst; int R, C, e, rt, ct;
    if (bid < NE * 96) {                       // W1: [384][256], 12x8 tiles
        e = bid / 96; int rem = bid % 96; rt = rem / 8; ct = rem % 8;
        src = W1; dst = w1t; R = D; C = H1;
    } else {                                   // Wh: [256][192], 8x6 tiles
        bid -= NE * 96;
        e = bid / 48; int rem = bid % 48; rt = rem / 6; ct = rem % 6;
        src = Wh; dst = wht; R = H1; C = H2;
    }
    const float* S  = src + ((size_t)e * R + rt * 32) * C + ct * 32;
    ushort_t*    Dp = dst + ((size_t)e * C + ct * 32) * R + rt * 32;
    {
        int row = t >> 3, c4 = (t & 7) * 4;
        float4 v = *(const float4*)(S + (size_t)row * C + c4);
        tile[row][c4 + 0] = v.x; tile[row][c4 + 1] = v.y;
        tile[row][c4 + 2] = v.z; tile[row][c4 + 3] = v.w;
    }
    __syncthreads();
    {
        int orow = t >> 3, k4 = (t & 7) * 4;
        ushort4 o;
        o.x = f2bf(tile[k4 + 0][orow]);
        o.y = f2bf(tile[k4 + 1][orow]);
        o.z = f2bf(tile[k4 + 2][orow]);
        o.w = f2bf(tile[k4 + 3][orow]);
        *(ushort4*)(Dp + (size_t)orow * R + k4) = o;
    }
}

__global__ __launch_bounds__(256, 3) void mlp_kernel(
    const float*    __restrict__ rep,
    const int*      __restrict__ counts,
    const int*      __restrict__ bucket,
    const ushort_t* __restrict__ w1t,      // [E][H1][D]  bf16
    const ushort_t* __restrict__ wht,      // [E][H2][H1] bf16
    const float*    __restrict__ b1,
    const float*    __restrict__ bh,
    const float*    __restrict__ W2,
    const float*    __restrict__ b2,
    float*          __restrict__ energy)
{
    // exact tile -> (species, tile) mapping
    const int c0 = counts[0], c1 = counts[1], c2 = counts[2], c3 = counts[3];
    const int t0 = (c0 + 63) >> 6, t1 = (c1 + 63) >> 6, t2 = (c2 + 63) >> 6, t3 = (c3 + 63) >> 6;
    int bid = blockIdx.x;
    int e, tile, n;
    if      (bid < t0)                { e = 0; tile = bid;                n = c0; }
    else if (bid < t0 + t1)           { e = 1; tile = bid - t0;           n = c1; }
    else if (bid < t0 + t1 + t2)      { e = 2; tile = bid - t0 - t1;      n = c2; }
    else if (bid < t0 + t1 + t2 + t3) { e = 3; tile = bid - t0 - t1 - t2; n = c3; }
    else return;
    const int base = tile * TA;

    const int t    = threadIdx.x;
    const int lane = t & 63;
    const int wv   = t >> 6;
    const int g    = lane >> 4;
    const int r    = lane & 15;

    __shared__ ushort_t Xt[2][TA * XLD];   // 10 KB dbuf
    __shared__ ushort_t H1t[TA * HLD];     // 33 KB
    __shared__ float    eparts[4 * TA];
    __shared__ int      idx_lds[TA];

    if (t < TA)
        idx_lds[t] = (base + t < n) ? bucket[(e << 15) + base + t] : -1;
    __syncthreads();

    // X staging coords
    const int xrow0 = t >> 3, xrow1 = 32 + xrow0, xc4 = (t & 7) * 4;
    int gi0 = idx_lds[xrow0]; if (gi0 < 0) gi0 = 0;
    int gi1 = idx_lds[xrow1]; if (gi1 < 0) gi1 = 0;
    const float* xp0 = rep + (size_t)gi0 * D + xc4;
    const float* xp1 = rep + (size_t)gi1 * D + xc4;

    // ===== phase 1: acc1[nn][m] = C1^T sub-tiles; A = W1-frag (global), B = X-frag (LDS)
    const ushort_t* a1p = w1t + ((size_t)e * H1 + wv * 64 + r) * D + g * 8;

    uint4 afc[4], afn[4];
    #pragma unroll
    for (int nn = 0; nn < 4; ++nn)
        afc[nn] = *(const uint4*)(a1p + nn * 16 * D);

    float4 rx0 = *(const float4*)(xp0);
    float4 rx1 = *(const float4*)(xp1);
    {
        ushort4 o;
        o.x = f2bf(rx0.x); o.y = f2bf(rx0.y); o.z = f2bf(rx0.z); o.w = f2bf(rx0.w);
        *(ushort4*)(&Xt[0][xrow0 * XLD + xc4]) = o;
        o.x = f2bf(rx1.x); o.y = f2bf(rx1.y); o.z = f2bf(rx1.z); o.w = f2bf(rx1.w);
        *(ushort4*)(&Xt[0][xrow1 * XLD + xc4]) = o;
    }
    __syncthreads();

    f32x4 acc1[4][4];
    #pragma unroll
    for (int nn = 0; nn < 4; ++nn)
        #pragma unroll
        for (int m = 0; m < 4; ++m)
            acc1[nn][m] = (f32x4){0.f, 0.f, 0.f, 0.f};

    for (int ks = 0; ks < 12; ++ks) {
        const int cur = ks & 1;
        if (ks < 11) {
            const int k0n = (ks + 1) * 32;
            rx0 = *(const float4*)(xp0 + k0n);
            rx1 = *(const float4*)(xp1 + k0n);
            #pragma unroll
            for (int nn = 0; nn < 4; ++nn)
                afn[nn] = *(const uint4*)(a1p + nn * 16 * D + k0n);
        }
        bf16x8 bw[4];
        #pragma unroll
        for (int m = 0; m < 4; ++m)
            bw[m] = *(const bf16x8*)(&Xt[cur][(m * 16 + r) * XLD + g * 8]);
        #pragma unroll
        for (int nn = 0; nn < 4; ++nn)
            #pragma unroll
            for (int m = 0; m < 4; ++m)
                acc1[nn][m] = __builtin_amdgcn_mfma_f32_16x16x32_bf16(
                    __builtin_bit_cast(bf16x8, afc[nn]), bw[m], acc1[nn][m], 0, 0, 0);
        if (ks < 11) {
            ushort4 o;
            o.x = f2bf(rx0.x); o.y = f2bf(rx0.y); o.z = f2bf(rx0.z); o.w = f2bf(rx0.w);
            *(ushort4*)(&Xt[cur ^ 1][xrow0 * XLD + xc4]) = o;
            o.x = f2bf(rx1.x); o.y = f2bf(rx1.y); o.z = f2bf(rx1.z); o.w = f2bf(rx1.w);
            *(ushort4*)(&Xt[cur ^ 1][xrow1 * XLD + xc4]) = o;
            __syncthreads();
            #pragma unroll
            for (int nn = 0; nn < 4; ++nn) afc[nn] = afn[nn];
        }
    }

    // +b1, packed b64 writes: lane holds 4 consecutive h rows (g*4+q), atom col = m*16+r
    float b1v[4][4];
    #pragma unroll
    for (int nn = 0; nn < 4; ++nn)
        #pragma unroll
        for (int q = 0; q < 4; ++q)
            b1v[nn][q] = b1[e * H1 + wv * 64 + nn * 16 + g * 4 + q];

    #pragma unroll
    for (int nn = 0; nn < 4; ++nn)
        #pragma unroll
        for (int m = 0; m < 4; ++m) {
            unsigned p0 = f2bf(acc1[nn][m][0] + b1v[nn][0]);
            unsigned p1 = f2bf(acc1[nn][m][1] + b1v[nn][1]);
            unsigned p2 = f2bf(acc1[nn][m][2] + b1v[nn][2]);
            unsigned p3 = f2bf(acc1[nn][m][3] + b1v[nn][3]);
            uint2 pk; pk.x = p0 | (p1 << 16); pk.y = p2 | (p3 << 16);
            *(uint2*)(&H1t[(m * 16 + r) * HLD + wv * 64 + nn * 16 + g * 4]) = pk;
        }
    __syncthreads();

    // ===== phase 2: acc2[nn][m] = C2^T; A = Wh-frag (global), B = H1-frag (LDS); no barriers
    const ushort_t* a2p = wht + ((size_t)e * H2 + wv * 48 + r) * H1 + g * 8;

    f32x4 acc2[3][4];
    #pragma unroll
    for (int nn = 0; nn < 3; ++nn)
        #pragma unroll
        for (int m = 0; m < 4; ++m)
            acc2[nn][m] = (f32x4){0.f, 0.f, 0.f, 0.f};

    uint4 af2c[3], af2n[3];
    #pragma unroll
    for (int nn = 0; nn < 3; ++nn)
        af2c[nn] = *(const uint4*)(a2p + nn * 16 * H1);

    for (int ks = 0; ks < 8; ++ks) {
        const int k0 = ks * 32;
        if (ks < 7) {
            #pragma unroll
            for (int nn = 0; nn < 3; ++nn)
                af2n[nn] = *(const uint4*)(a2p + nn * 16 * H1 + k0 + 32);
        }
        bf16x8 bw2[4];
        #pragma unroll
        for (int m = 0; m < 4; ++m)
            bw2[m] = *(const bf16x8*)(&H1t[(m * 16 + r) * HLD + k0 + g * 8]);
        #pragma unroll
        for (int nn = 0; nn < 3; ++nn)
            #pragma unroll
            for (int m = 0; m < 4; ++m)
                acc2[nn][m] = __builtin_amdgcn_mfma_f32_16x16x32_bf16(
                    __builtin_bit_cast(bf16x8, af2c[nn]), bw2[m], acc2[nn][m], 0, 0, 0);
        if (ks < 7) {
            #pragma unroll
            for (int nn = 0; nn < 3; ++nn) af2c[nn] = af2n[nn];
        }
    }

    // ===== epilogue: relu(C2^T + bh)·W2 summed over this wave's 48 h2 rows
    float bhv[3][4], w2v[3][4];
    #pragma unroll
    for (int nn = 0; nn < 3; ++nn)
        #pragma unroll
        for (int q = 0; q < 4; ++q) {
            int h2i = e * H2 + wv * 48 + nn * 16 + g * 4 + q;
            bhv[nn][q] = bh[h2i];
            w2v[nn][q] = W2[h2i];
        }
    const float b2e = b2[e];

    #pragma unroll
    for (int m = 0; m < 4; ++m) {
        float s = 0.f;
        #pragma unroll
        for (int nn = 0; nn < 3; ++nn)
            #pragma unroll
            for (int q = 0; q < 4; ++q) {
                float z = acc2[nn][m][q] + bhv[nn][q];
                z = fmaxf(z, 0.f);
                s += z * w2v[nn][q];
            }
        s += __shfl_xor(s, 16, 64);   // reduce across g
        s += __shfl_xor(s, 32, 64);
        if (lane < 16) eparts[wv * TA + m * 16 + r] = s;
    }
    __syncthreads();
    if (t < TA) {
        int gi = idx_lds[t];
        if (gi >= 0)
            energy[gi] = eparts[t] + eparts[TA + t] + eparts[2 * TA + t]
                       + eparts[3 * TA + t] + b2e;
    }
}

__global__ void reduce_kernel(const float* __restrict__ energy, float* __restrict__ out) {
    const int b = blockIdx.x, t = threadIdx.x;
    float s = 0.f;
    for (int i = t; i < NA; i += 256) s += energy[b * NA + i];
    for (int off = 32; off > 0; off >>= 1) s += __shfl_down(s, off, 64);
    __shared__ float ws[4];
    if ((t & 63) == 0) ws[t >> 6] = s;
    __syncthreads();
    if (t == 0) out[b] = ws[0] + ws[1] + ws[2] + ws[3];
}

extern "C" void kernel_launch(void* const* d_in, const int* in_sizes, int n_in,
                              void* d_out, int out_size, void* d_ws, size_t ws_size,
                              hipStream_t stream) {
    const float* rep     = (const float*)d_in[0];
    const int*   species = (const int*)  d_in[1];
    const float* W1      = (const float*)d_in[2];
    const float* b1      = (const float*)d_in[3];
    const float* Wh      = (const float*)d_in[4];
    const float* bh      = (const float*)d_in[5];
    const float* W2      = (const float*)d_in[6];
    const float* b2      = (const float*)d_in[7];
    float* out = (float*)d_out;

    char* ws = (char*)d_ws;
    int*      counts  = (int*)      (ws + 0);
    int*      bucket  = (int*)      (ws + 64);          // 512 KB
    float*    energy  = (float*)    (ws + 524352);      // 128 KB
    ushort_t* w1t     = (ushort_t*) (ws + 655424);      // 768 KB
    ushort_t* wht     = (ushort_t*) (ws + 1441856);     // 384 KB

    zero_kernel<<<1, 64, 0, stream>>>(counts);
    scatter_kernel<<<NATOMS / 256, 256, 0, stream>>>(species, counts, bucket);
    transpose_kernel<<<NE * 96 + NE * 48, 256, 0, stream>>>(W1, Wh, w1t, wht);
    mlp_kernel<<<NGRID, 256, 0, stream>>>(rep, counts, bucket, w1t, wht,
                                          b1, bh, W2, b2, energy);
    reduce_kernel<<<NB, 256, 0, stream>>>(energy, out);
}